// Round 1
// baseline (377.767 us; speedup 1.0000x reference)
//
#include <hip/hip_runtime.h>
#include <hip/hip_bf16.h>
#include <stdint.h>

#define N_TOK 16384
#define HDIM  1024
#define NE    8

typedef __attribute__((ext_vector_type(8))) short          bf16x8;
typedef __attribute__((ext_vector_type(8))) unsigned short ushort8;
typedef __attribute__((ext_vector_type(4))) float          f32x4;

__device__ __forceinline__ unsigned short f2bf(float f) {
  union { float f; uint32_t u; } c; c.f = f;
  uint32_t u = c.u;
  uint32_t r = (u + 0x7fffu + ((u >> 16) & 1u)) >> 16;
  return (unsigned short)r;
}

__device__ __forceinline__ void gload_lds16(const void* g, void* l) {
  __builtin_amdgcn_global_load_lds((const __attribute__((address_space(1))) void*)g,
                                   (__attribute__((address_space(3))) void*)l, 16, 0, 0);
}

// ---------------------------------------------------------------------------
// Gate: logits = tokens @ gate_w^T (f64 accum), top-1 argmax, rank via atomic.
// Also converts tokens f32 -> bf16 (token order) for GEMM1 staging.
// One wave per token; 4 tokens per 256-thread block.
// ---------------------------------------------------------------------------
__global__ __launch_bounds__(256) void gate_kernel(
    const float* __restrict__ tokens, const float* __restrict__ gate_w,
    unsigned short* __restrict__ tokB, int* __restrict__ eid,
    int* __restrict__ rank, int* __restrict__ counts)
{
  int wid  = threadIdx.x >> 6;
  int lane = threadIdx.x & 63;
  int n    = blockIdx.x * 4 + wid;

  const float4* tp = (const float4*)(tokens + (size_t)n * HDIM + lane * 16);
  float x[16];
#pragma unroll
  for (int i = 0; i < 4; ++i) {
    float4 v = tp[i];
    x[i*4+0] = v.x; x[i*4+1] = v.y; x[i*4+2] = v.z; x[i*4+3] = v.w;
  }
  // bf16 conversion + store (2 x 16B)
  ushort8 o0, o1;
#pragma unroll
  for (int i = 0; i < 8; ++i) { o0[i] = f2bf(x[i]); o1[i] = f2bf(x[8+i]); }
  ushort8* dst = (ushort8*)(tokB + (size_t)n * HDIM + lane * 16);
  dst[0] = o0; dst[1] = o1;

  double acc[NE];
#pragma unroll
  for (int e = 0; e < NE; ++e) {
    const float4* gp = (const float4*)(gate_w + e * HDIM + lane * 16);
    double a = 0.0;
#pragma unroll
    for (int i = 0; i < 4; ++i) {
      float4 g = gp[i];
      a += (double)x[i*4+0] * g.x + (double)x[i*4+1] * g.y
         + (double)x[i*4+2] * g.z + (double)x[i*4+3] * g.w;
    }
    acc[e] = a;
  }
#pragma unroll
  for (int off = 32; off; off >>= 1) {
#pragma unroll
    for (int e = 0; e < NE; ++e) acc[e] += __shfl_xor(acc[e], off);
  }
  if (lane == 0) {
    int best = 0; double bv = acc[0];
#pragma unroll
    for (int e = 1; e < NE; ++e) if (acc[e] > bv) { bv = acc[e]; best = e; }
    eid[n]  = best;
    rank[n] = atomicAdd(&counts[best], 1);
  }
}

// meta[0..7] = counts, meta[8..15] = exclusive offsets
__global__ void scan_kernel(int* meta) {
  if (threadIdx.x == 0) {
    int run = 0;
    for (int e = 0; e < NE; ++e) { meta[8 + e] = run; run += meta[e]; }
  }
}

__global__ __launch_bounds__(256) void perm_kernel(
    const int* __restrict__ meta, const int* __restrict__ eid,
    const int* __restrict__ rank, int* __restrict__ topos)
{
  int n = blockIdx.x * 256 + threadIdx.x;
  topos[meta[8 + eid[n]] + rank[n]] = n;
}

// f32 -> bf16, 8 elements/thread
__global__ __launch_bounds__(256) void cvt_kernel(
    const float* __restrict__ src, unsigned short* __restrict__ dst)
{
  size_t i = (size_t)blockIdx.x * 256 + threadIdx.x;
  const float4* s = (const float4*)src + i * 2;
  float4 a = s[0], b = s[1];
  ushort8 o;
  o[0] = f2bf(a.x); o[1] = f2bf(a.y); o[2] = f2bf(a.z); o[3] = f2bf(a.w);
  o[4] = f2bf(b.x); o[5] = f2bf(b.y); o[6] = f2bf(b.z); o[7] = f2bf(b.w);
  ((ushort8*)dst)[i] = o;
}

// ---------------------------------------------------------------------------
// Grouped GEMM1: H[pos] = relu(tokens[topos[pos]] @ w1[e]^T + b1[e])  (bf16 out)
// 128x128 tile, BK=64, 4 waves (2x2), 4x4 frags of mfma 16x16x32 bf16.
// Grid = E * 128 row-tiles * 8 n-tiles; empty tiles exit.
// ---------------------------------------------------------------------------
#define GRID_GEMM (NE * 128 * 8)

__global__ __launch_bounds__(256) void gemm1_kernel(
    const unsigned short* __restrict__ tokB,  // [N][H] token order
    const unsigned short* __restrict__ w1B,   // [E][H][H]
    const float* __restrict__ b1,             // [E][H]
    const int* __restrict__ meta,
    const int* __restrict__ topos,
    unsigned short* __restrict__ Hbuf)        // [N][H] compacted
{
  int bid = blockIdx.x;
  int e   = bid >> 10;
  int rem = bid & 1023;
  int mt  = rem >> 3, nt = rem & 7;
  int cnt = meta[e];
  if (mt * 128 >= cnt) return;
  int base = meta[8 + e];

  __shared__ unsigned short Alds[128 * 64];
  __shared__ unsigned short Blds[128 * 64];

  int t     = threadIdx.x;
  int rowA0 = t >> 3;   // 0..31
  int kc    = t & 7;    // 16B chunk

  int tokr[4];
#pragma unroll
  for (int r = 0; r < 4; ++r) {
    int pos = base + mt * 128 + rowA0 + 32 * r;
    if (pos > N_TOK - 1) pos = N_TOK - 1;
    tokr[r] = topos[pos];
  }
  const unsigned short* bsrc =
      w1B + ((size_t)e << 20) + (size_t)(nt * 128 + rowA0) * HDIM + kc * 8;

  int lane = t & 63, wid = t >> 6;
  int wr = wid >> 1, wc = wid & 1;
  f32x4 acc[4][4] = {};

  int arow = wr * 64 + (lane & 15);
  int brow = wc * 64 + (lane & 15);
  int acol = (lane >> 4) * 8;

  for (int kt = 0; kt < 16; ++kt) {
    __syncthreads();
#pragma unroll
    for (int r = 0; r < 4; ++r)
      gload_lds16(tokB + (size_t)tokr[r] * HDIM + kt * 64 + kc * 8,
                  Alds + (rowA0 + 32 * r) * 64 + kc * 8);
#pragma unroll
    for (int r = 0; r < 4; ++r)
      gload_lds16(bsrc + kt * 64 + (size_t)(32 * r) * HDIM,
                  Blds + (rowA0 + 32 * r) * 64 + kc * 8);
    __syncthreads();
#pragma unroll
    for (int ks = 0; ks < 2; ++ks) {
      bf16x8 af[4], bv[4];
#pragma unroll
      for (int mi = 0; mi < 4; ++mi)
        af[mi] = *(const bf16x8*)(Alds + (arow + mi * 16) * 64 + ks * 32 + acol);
#pragma unroll
      for (int ni = 0; ni < 4; ++ni)
        bv[ni] = *(const bf16x8*)(Blds + (brow + ni * 16) * 64 + ks * 32 + acol);
#pragma unroll
      for (int mi = 0; mi < 4; ++mi)
#pragma unroll
        for (int ni = 0; ni < 4; ++ni)
          acc[mi][ni] = __builtin_amdgcn_mfma_f32_16x16x32_bf16(
              af[mi], bv[ni], acc[mi][ni], 0, 0, 0);
    }
  }

  int crow0 = wr * 64 + (lane >> 4) * 4;
  int ccol0 = wc * 64 + (lane & 15);
  float bias[4];
#pragma unroll
  for (int ni = 0; ni < 4; ++ni)
    bias[ni] = b1[e * HDIM + nt * 128 + ccol0 + ni * 16];
#pragma unroll
  for (int mi = 0; mi < 4; ++mi) {
#pragma unroll
    for (int j = 0; j < 4; ++j) {
      int row = crow0 + mi * 16 + j;
      if (mt * 128 + row < cnt) {
        size_t orow = (size_t)(base + mt * 128 + row) * HDIM + nt * 128;
#pragma unroll
        for (int ni = 0; ni < 4; ++ni) {
          float v = acc[mi][ni][j] + bias[ni];
          v = v > 0.f ? v : 0.f;
          Hbuf[orow + ccol0 + ni * 16] = f2bf(v);
        }
      }
    }
  }
}

// ---------------------------------------------------------------------------
// Grouped GEMM2: out[topos[pos]] = H[pos] @ w2[e]^T + b2[e]   (f32 out)
// ---------------------------------------------------------------------------
__global__ __launch_bounds__(256) void gemm2_kernel(
    const unsigned short* __restrict__ Hbuf,  // [N][H] compacted
    const unsigned short* __restrict__ w2B,   // [E][H][H]
    const float* __restrict__ b2,             // [E][H]
    const int* __restrict__ meta,
    const int* __restrict__ topos,
    float* __restrict__ out)                  // [N][H] token order
{
  int bid = blockIdx.x;
  int e   = bid >> 10;
  int rem = bid & 1023;
  int mt  = rem >> 3, nt = rem & 7;
  int cnt = meta[e];
  if (mt * 128 >= cnt) return;
  int base = meta[8 + e];

  __shared__ unsigned short Alds[128 * 64];
  __shared__ unsigned short Blds[128 * 64];

  int t     = threadIdx.x;
  int rowA0 = t >> 3;
  int kc    = t & 7;

  int arows[4];
#pragma unroll
  for (int r = 0; r < 4; ++r) {
    int pos = base + mt * 128 + rowA0 + 32 * r;
    arows[r] = pos > N_TOK - 1 ? N_TOK - 1 : pos;
  }
  const unsigned short* bsrc =
      w2B + ((size_t)e << 20) + (size_t)(nt * 128 + rowA0) * HDIM + kc * 8;

  int lane = t & 63, wid = t >> 6;
  int wr = wid >> 1, wc = wid & 1;
  f32x4 acc[4][4] = {};

  int arow = wr * 64 + (lane & 15);
  int brow = wc * 64 + (lane & 15);
  int acol = (lane >> 4) * 8;

  for (int kt = 0; kt < 16; ++kt) {
    __syncthreads();
#pragma unroll
    for (int r = 0; r < 4; ++r)
      gload_lds16(Hbuf + (size_t)arows[r] * HDIM + kt * 64 + kc * 8,
                  Alds + (rowA0 + 32 * r) * 64 + kc * 8);
#pragma unroll
    for (int r = 0; r < 4; ++r)
      gload_lds16(bsrc + kt * 64 + (size_t)(32 * r) * HDIM,
                  Blds + (rowA0 + 32 * r) * 64 + kc * 8);
    __syncthreads();
#pragma unroll
    for (int ks = 0; ks < 2; ++ks) {
      bf16x8 af[4], bv[4];
#pragma unroll
      for (int mi = 0; mi < 4; ++mi)
        af[mi] = *(const bf16x8*)(Alds + (arow + mi * 16) * 64 + ks * 32 + acol);
#pragma unroll
      for (int ni = 0; ni < 4; ++ni)
        bv[ni] = *(const bf16x8*)(Blds + (brow + ni * 16) * 64 + ks * 32 + acol);
#pragma unroll
      for (int mi = 0; mi < 4; ++mi)
#pragma unroll
        for (int ni = 0; ni < 4; ++ni)
          acc[mi][ni] = __builtin_amdgcn_mfma_f32_16x16x32_bf16(
              af[mi], bv[ni], acc[mi][ni], 0, 0, 0);
    }
  }

  int crow0 = wr * 64 + (lane >> 4) * 4;
  int ccol0 = wc * 64 + (lane & 15);
  float bias[4];
#pragma unroll
  for (int ni = 0; ni < 4; ++ni)
    bias[ni] = b2[e * HDIM + nt * 128 + ccol0 + ni * 16];
#pragma unroll
  for (int mi = 0; mi < 4; ++mi) {
#pragma unroll
    for (int j = 0; j < 4; ++j) {
      int row = crow0 + mi * 16 + j;
      if (mt * 128 + row < cnt) {
        int tok = topos[base + mt * 128 + row];
        size_t orow = (size_t)tok * HDIM + nt * 128;
#pragma unroll
        for (int ni = 0; ni < 4; ++ni)
          out[orow + ccol0 + ni * 16] = acc[mi][ni][j] + bias[ni];
      }
    }
  }
}

extern "C" void kernel_launch(void* const* d_in, const int* in_sizes, int n_in,
                              void* d_out, int out_size, void* d_ws, size_t ws_size,
                              hipStream_t stream) {
  (void)in_sizes; (void)n_in; (void)out_size; (void)ws_size;
  const float* tokens = (const float*)d_in[0];
  const float* gate_w = (const float*)d_in[1];
  const float* w1     = (const float*)d_in[2];
  const float* b1     = (const float*)d_in[3];
  const float* w2     = (const float*)d_in[4];
  const float* b2     = (const float*)d_in[5];
  float* out          = (float*)d_out;

  char* ws = (char*)d_ws;
  size_t o = 0;
  int* meta  = (int*)(ws + o); o += 256;                   // counts[8] + offsets[8]
  int* eid   = (int*)(ws + o); o += (size_t)N_TOK * 4;
  int* rank  = (int*)(ws + o); o += (size_t)N_TOK * 4;
  int* topos = (int*)(ws + o); o += (size_t)N_TOK * 4;
  unsigned short* tokB = (unsigned short*)(ws + o); o += (size_t)N_TOK * HDIM * 2;
  unsigned short* w1B  = (unsigned short*)(ws + o); o += (size_t)NE * HDIM * HDIM * 2;
  unsigned short* w2B  = (unsigned short*)(ws + o); o += (size_t)NE * HDIM * HDIM * 2;
  unsigned short* Hbuf = (unsigned short*)(ws + o); o += (size_t)N_TOK * HDIM * 2;

  hipMemsetAsync(meta, 0, 64, stream);
  gate_kernel<<<N_TOK / 4, 256, 0, stream>>>(tokens, gate_w, tokB, eid, rank, meta);
  cvt_kernel<<<4096, 256, 0, stream>>>(w1, w1B);
  cvt_kernel<<<4096, 256, 0, stream>>>(w2, w2B);
  scan_kernel<<<1, 64, 0, stream>>>(meta);
  perm_kernel<<<N_TOK / 256, 256, 0, stream>>>(meta, eid, rank, topos);
  gemm1_kernel<<<GRID_GEMM, 256, 0, stream>>>(tokB, w1B, b1, meta, topos, Hbuf);
  gemm2_kernel<<<GRID_GEMM, 256, 0, stream>>>(Hbuf, w2B, b2, meta, topos, out);
}

// Round 2
// 215.533 us; speedup vs baseline: 1.7527x; 1.7527x over previous
//
#include <hip/hip_runtime.h>
#include <hip/hip_bf16.h>
#include <stdint.h>

#define N_TOK 16384
#define HDIM  1024
#define NE    8

typedef __attribute__((ext_vector_type(8))) short          bf16x8;
typedef __attribute__((ext_vector_type(8))) unsigned short ushort8;
typedef __attribute__((ext_vector_type(4))) unsigned short ushort4v;
typedef __attribute__((ext_vector_type(4))) float          f32x4;

__device__ __forceinline__ unsigned short f2bf(float f) {
  union { float f; uint32_t u; } c; c.f = f;
  uint32_t u = c.u;
  uint32_t r = (u + 0x7fffu + ((u >> 16) & 1u)) >> 16;
  return (unsigned short)r;
}

__device__ __forceinline__ void gload_lds16(const void* g, void* l) {
  __builtin_amdgcn_global_load_lds((const __attribute__((address_space(1))) void*)g,
                                   (__attribute__((address_space(3))) void*)l, 16, 0, 0);
}

// ---------------------------------------------------------------------------
// Gate: logits = tokens @ gate_w^T (f64 accum), top-1 argmax -> eid only.
// Fuses token f32->bf16 conversion. Fully coalesced: lane-consecutive float4.
// One wave per token; 4 tokens per 256-thread block. NO global atomics here.
// ---------------------------------------------------------------------------
__global__ __launch_bounds__(256) void gate_kernel(
    const float* __restrict__ tokens, const float* __restrict__ gate_w,
    unsigned short* __restrict__ tokB, int* __restrict__ eid)
{
  int wid  = threadIdx.x >> 6;
  int lane = threadIdx.x & 63;
  int n    = blockIdx.x * 4 + wid;

  const float* trow = tokens + (size_t)n * HDIM;
  float4 x[4];
#pragma unroll
  for (int i = 0; i < 4; ++i)
    x[i] = *(const float4*)(trow + i * 256 + lane * 4);

  // bf16 conversion + coalesced 8B stores
  unsigned short* drow = tokB + (size_t)n * HDIM;
#pragma unroll
  for (int i = 0; i < 4; ++i) {
    ushort4v o;
    o[0] = f2bf(x[i].x); o[1] = f2bf(x[i].y);
    o[2] = f2bf(x[i].z); o[3] = f2bf(x[i].w);
    *(ushort4v*)(drow + i * 256 + lane * 4) = o;
  }

  double acc[NE];
#pragma unroll
  for (int e = 0; e < NE; ++e) {
    const float* grow = gate_w + e * HDIM;
    double a = 0.0;
#pragma unroll
    for (int i = 0; i < 4; ++i) {
      float4 g = *(const float4*)(grow + i * 256 + lane * 4);
      a += (double)x[i].x * g.x + (double)x[i].y * g.y
         + (double)x[i].z * g.z + (double)x[i].w * g.w;
    }
    acc[e] = a;
  }
#pragma unroll
  for (int off = 32; off; off >>= 1) {
#pragma unroll
    for (int e = 0; e < NE; ++e) acc[e] += __shfl_xor(acc[e], off);
  }
  if (lane == 0) {
    int best = 0; double bv = acc[0];
#pragma unroll
    for (int e = 1; e < NE; ++e) if (acc[e] > bv) { bv = acc[e]; best = e; }
    eid[n] = best;
  }
}

// ---------------------------------------------------------------------------
// Rank: hierarchical. LDS histogram per block (256 tokens) -> intra-block
// rank; ONE global atomic per expert per block reserves a contiguous chunk.
// 64 blocks -> 512 global atomics total (vs 16384 before).
// ---------------------------------------------------------------------------
__global__ __launch_bounds__(256) void rank_kernel(
    const int* __restrict__ eid, int* __restrict__ rank, int* __restrict__ counts)
{
  __shared__ int h[NE];
  __shared__ int bbase[NE];
  int t = threadIdx.x;
  int n = blockIdx.x * 256 + t;
  if (t < NE) h[t] = 0;
  __syncthreads();
  int e = eid[n];
  int r = atomicAdd(&h[e], 1);
  __syncthreads();
  if (t < NE) bbase[t] = atomicAdd(&counts[t], h[t]);
  __syncthreads();
  rank[n] = bbase[e] + r;
}

// meta[0..7] = counts, meta[8..15] = exclusive offsets
__global__ void scan_kernel(int* meta) {
  if (threadIdx.x == 0) {
    int run = 0;
    for (int e = 0; e < NE; ++e) { meta[8 + e] = run; run += meta[e]; }
  }
}

__global__ __launch_bounds__(256) void perm_kernel(
    const int* __restrict__ meta, const int* __restrict__ eid,
    const int* __restrict__ rank, int* __restrict__ topos)
{
  int n = blockIdx.x * 256 + threadIdx.x;
  topos[meta[8 + eid[n]] + rank[n]] = n;
}

// f32 -> bf16, 8 elements/thread
__global__ __launch_bounds__(256) void cvt_kernel(
    const float* __restrict__ src, unsigned short* __restrict__ dst)
{
  size_t i = (size_t)blockIdx.x * 256 + threadIdx.x;
  const float4* s = (const float4*)src + i * 2;
  float4 a = s[0], b = s[1];
  ushort8 o;
  o[0] = f2bf(a.x); o[1] = f2bf(a.y); o[2] = f2bf(a.z); o[3] = f2bf(a.w);
  o[4] = f2bf(b.x); o[5] = f2bf(b.y); o[6] = f2bf(b.z); o[7] = f2bf(b.w);
  ((ushort8*)dst)[i] = o;
}

// ---------------------------------------------------------------------------
// Grouped GEMM1: H[pos] = relu(tokens[topos[pos]] @ w1[e]^T + b1[e])  (bf16 out)
// 128x128 tile, BK=64, 4 waves (2x2), 4x4 frags of mfma 16x16x32 bf16.
// ---------------------------------------------------------------------------
#define GRID_GEMM (NE * 128 * 8)

__global__ __launch_bounds__(256) void gemm1_kernel(
    const unsigned short* __restrict__ tokB,  // [N][H] token order
    const unsigned short* __restrict__ w1B,   // [E][H][H]
    const float* __restrict__ b1,             // [E][H]
    const int* __restrict__ meta,
    const int* __restrict__ topos,
    unsigned short* __restrict__ Hbuf)        // [N][H] compacted
{
  int bid = blockIdx.x;
  int e   = bid >> 10;
  int rem = bid & 1023;
  int mt  = rem >> 3, nt = rem & 7;
  int cnt = meta[e];
  if (mt * 128 >= cnt) return;
  int base = meta[8 + e];

  __shared__ unsigned short Alds[128 * 64];
  __shared__ unsigned short Blds[128 * 64];

  int t     = threadIdx.x;
  int rowA0 = t >> 3;   // 0..31
  int kc    = t & 7;    // 16B chunk

  int tokr[4];
#pragma unroll
  for (int r = 0; r < 4; ++r) {
    int pos = base + mt * 128 + rowA0 + 32 * r;
    if (pos > N_TOK - 1) pos = N_TOK - 1;
    tokr[r] = topos[pos];
  }
  const unsigned short* bsrc =
      w1B + ((size_t)e << 20) + (size_t)(nt * 128 + rowA0) * HDIM + kc * 8;

  int lane = t & 63, wid = t >> 6;
  int wr = wid >> 1, wc = wid & 1;
  f32x4 acc[4][4] = {};

  int arow = wr * 64 + (lane & 15);
  int brow = wc * 64 + (lane & 15);
  int acol = (lane >> 4) * 8;

  for (int kt = 0; kt < 16; ++kt) {
    __syncthreads();
#pragma unroll
    for (int r = 0; r < 4; ++r)
      gload_lds16(tokB + (size_t)tokr[r] * HDIM + kt * 64 + kc * 8,
                  Alds + (rowA0 + 32 * r) * 64 + kc * 8);
#pragma unroll
    for (int r = 0; r < 4; ++r)
      gload_lds16(bsrc + kt * 64 + (size_t)(32 * r) * HDIM,
                  Blds + (rowA0 + 32 * r) * 64 + kc * 8);
    __syncthreads();
#pragma unroll
    for (int ks = 0; ks < 2; ++ks) {
      bf16x8 af[4], bv[4];
#pragma unroll
      for (int mi = 0; mi < 4; ++mi)
        af[mi] = *(const bf16x8*)(Alds + (arow + mi * 16) * 64 + ks * 32 + acol);
#pragma unroll
      for (int ni = 0; ni < 4; ++ni)
        bv[ni] = *(const bf16x8*)(Blds + (brow + ni * 16) * 64 + ks * 32 + acol);
#pragma unroll
      for (int mi = 0; mi < 4; ++mi)
#pragma unroll
        for (int ni = 0; ni < 4; ++ni)
          acc[mi][ni] = __builtin_amdgcn_mfma_f32_16x16x32_bf16(
              af[mi], bv[ni], acc[mi][ni], 0, 0, 0);
    }
  }

  int crow0 = wr * 64 + (lane >> 4) * 4;
  int ccol0 = wc * 64 + (lane & 15);
  float bias[4];
#pragma unroll
  for (int ni = 0; ni < 4; ++ni)
    bias[ni] = b1[e * HDIM + nt * 128 + ccol0 + ni * 16];
#pragma unroll
  for (int mi = 0; mi < 4; ++mi) {
#pragma unroll
    for (int j = 0; j < 4; ++j) {
      int row = crow0 + mi * 16 + j;
      if (mt * 128 + row < cnt) {
        size_t orow = (size_t)(base + mt * 128 + row) * HDIM + nt * 128;
#pragma unroll
        for (int ni = 0; ni < 4; ++ni) {
          float v = acc[mi][ni][j] + bias[ni];
          v = v > 0.f ? v : 0.f;
          Hbuf[orow + ccol0 + ni * 16] = f2bf(v);
        }
      }
    }
  }
}

// ---------------------------------------------------------------------------
// Grouped GEMM2: out[topos[pos]] = H[pos] @ w2[e]^T + b2[e]   (f32 out)
// ---------------------------------------------------------------------------
__global__ __launch_bounds__(256) void gemm2_kernel(
    const unsigned short* __restrict__ Hbuf,  // [N][H] compacted
    const unsigned short* __restrict__ w2B,   // [E][H][H]
    const float* __restrict__ b2,             // [E][H]
    const int* __restrict__ meta,
    const int* __restrict__ topos,
    float* __restrict__ out)                  // [N][H] token order
{
  int bid = blockIdx.x;
  int e   = bid >> 10;
  int rem = bid & 1023;
  int mt  = rem >> 3, nt = rem & 7;
  int cnt = meta[e];
  if (mt * 128 >= cnt) return;
  int base = meta[8 + e];

  __shared__ unsigned short Alds[128 * 64];
  __shared__ unsigned short Blds[128 * 64];

  int t     = threadIdx.x;
  int rowA0 = t >> 3;
  int kc    = t & 7;

  int arows[4];
#pragma unroll
  for (int r = 0; r < 4; ++r) {
    int pos = base + mt * 128 + rowA0 + 32 * r;
    arows[r] = pos > N_TOK - 1 ? N_TOK - 1 : pos;
  }
  const unsigned short* bsrc =
      w2B + ((size_t)e << 20) + (size_t)(nt * 128 + rowA0) * HDIM + kc * 8;

  int lane = t & 63, wid = t >> 6;
  int wr = wid >> 1, wc = wid & 1;
  f32x4 acc[4][4] = {};

  int arow = wr * 64 + (lane & 15);
  int brow = wc * 64 + (lane & 15);
  int acol = (lane >> 4) * 8;

  for (int kt = 0; kt < 16; ++kt) {
    __syncthreads();
#pragma unroll
    for (int r = 0; r < 4; ++r)
      gload_lds16(Hbuf + (size_t)arows[r] * HDIM + kt * 64 + kc * 8,
                  Alds + (rowA0 + 32 * r) * 64 + kc * 8);
#pragma unroll
    for (int r = 0; r < 4; ++r)
      gload_lds16(bsrc + kt * 64 + (size_t)(32 * r) * HDIM,
                  Blds + (rowA0 + 32 * r) * 64 + kc * 8);
    __syncthreads();
#pragma unroll
    for (int ks = 0; ks < 2; ++ks) {
      bf16x8 af[4], bv[4];
#pragma unroll
      for (int mi = 0; mi < 4; ++mi)
        af[mi] = *(const bf16x8*)(Alds + (arow + mi * 16) * 64 + ks * 32 + acol);
#pragma unroll
      for (int ni = 0; ni < 4; ++ni)
        bv[ni] = *(const bf16x8*)(Blds + (brow + ni * 16) * 64 + ks * 32 + acol);
#pragma unroll
      for (int mi = 0; mi < 4; ++mi)
#pragma unroll
        for (int ni = 0; ni < 4; ++ni)
          acc[mi][ni] = __builtin_amdgcn_mfma_f32_16x16x32_bf16(
              af[mi], bv[ni], acc[mi][ni], 0, 0, 0);
    }
  }

  int crow0 = wr * 64 + (lane >> 4) * 4;
  int ccol0 = wc * 64 + (lane & 15);
  float bias[4];
#pragma unroll
  for (int ni = 0; ni < 4; ++ni)
    bias[ni] = b2[e * HDIM + nt * 128 + ccol0 + ni * 16];
#pragma unroll
  for (int mi = 0; mi < 4; ++mi) {
#pragma unroll
    for (int j = 0; j < 4; ++j) {
      int row = crow0 + mi * 16 + j;
      if (mt * 128 + row < cnt) {
        int tok = topos[base + mt * 128 + row];
        size_t orow = (size_t)tok * HDIM + nt * 128;
#pragma unroll
        for (int ni = 0; ni < 4; ++ni)
          out[orow + ccol0 + ni * 16] = acc[mi][ni][j] + bias[ni];
      }
    }
  }
}

extern "C" void kernel_launch(void* const* d_in, const int* in_sizes, int n_in,
                              void* d_out, int out_size, void* d_ws, size_t ws_size,
                              hipStream_t stream) {
  (void)in_sizes; (void)n_in; (void)out_size; (void)ws_size;
  const float* tokens = (const float*)d_in[0];
  const float* gate_w = (const float*)d_in[1];
  const float* w1     = (const float*)d_in[2];
  const float* b1     = (const float*)d_in[3];
  const float* w2     = (const float*)d_in[4];
  const float* b2     = (const float*)d_in[5];
  float* out          = (float*)d_out;

  char* ws = (char*)d_ws;
  size_t o = 0;
  int* meta  = (int*)(ws + o); o += 256;                   // counts[8] + offsets[8]
  int* eid   = (int*)(ws + o); o += (size_t)N_TOK * 4;
  int* rank  = (int*)(ws + o); o += (size_t)N_TOK * 4;
  int* topos = (int*)(ws + o); o += (size_t)N_TOK * 4;
  unsigned short* tokB = (unsigned short*)(ws + o); o += (size_t)N_TOK * HDIM * 2;
  unsigned short* w1B  = (unsigned short*)(ws + o); o += (size_t)NE * HDIM * HDIM * 2;
  unsigned short* w2B  = (unsigned short*)(ws + o); o += (size_t)NE * HDIM * HDIM * 2;
  unsigned short* Hbuf = (unsigned short*)(ws + o); o += (size_t)N_TOK * HDIM * 2;

  hipMemsetAsync(meta, 0, 64, stream);
  gate_kernel<<<N_TOK / 4, 256, 0, stream>>>(tokens, gate_w, tokB, eid);
  cvt_kernel<<<4096, 256, 0, stream>>>(w1, w1B);
  cvt_kernel<<<4096, 256, 0, stream>>>(w2, w2B);
  rank_kernel<<<N_TOK / 256, 256, 0, stream>>>(eid, rank, meta);
  scan_kernel<<<1, 64, 0, stream>>>(meta);
  perm_kernel<<<N_TOK / 256, 256, 0, stream>>>(meta, eid, rank, topos);
  gemm1_kernel<<<GRID_GEMM, 256, 0, stream>>>(tokB, w1B, b1, meta, topos, Hbuf);
  gemm2_kernel<<<GRID_GEMM, 256, 0, stream>>>(Hbuf, w2B, b2, meta, topos, out);
}